// Round 5
// baseline (269.152 us; speedup 1.0000x reference)
//
#include <hip/hip_runtime.h>

#define C_NUM 1000
#define D_DIM 128
#define MOMENTUM 0.9f
#define KCHUNKS 32      // blocks per class in the partial reduce
#define NBLK 256        // partition chunks over N
#define STAGE_MAX 7936  // max chunk size the LDS-staged place supports
#define SLICE 256       // order entries staged to LDS per pass in gather

// ws layout (4-byte words):
//   [0]                  counts[C]
//   [C]                  offsets[C]
//   [2C]                 cursor[C]      (fallback path only)
//   [3C]                 mat[C * NBLK]  per-(class,chunk) counts -> excl. prefix
//   [3C + C*NBLK]        sums_part[K * C * D] (float)
//   [... + K*C*D]        order[N]

// ---------- phase 1: per-chunk class histogram ----------
__global__ __launch_bounds__(256) void chunk_hist_kernel(
        const int* __restrict__ labels, int n, int* __restrict__ mat) {
    __shared__ int h[C_NUM];
    int b = blockIdx.x;
    int chunk = (n + NBLK - 1) / NBLK;
    int start = b * chunk, end = min(start + chunk, n);
    for (int i = threadIdx.x; i < C_NUM; i += 256) h[i] = 0;
    __syncthreads();
    for (int i = start + threadIdx.x; i < end; i += 256)
        atomicAdd(&h[labels[i]], 1);
    __syncthreads();
    for (int c = threadIdx.x; c < C_NUM; c += 256)
        mat[c * NBLK + b] = h[c];
}

// ---------- phase 2: per-class exclusive scan over chunks ----------
__global__ __launch_bounds__(256) void scan_mat_kernel(
        int* __restrict__ mat, int* __restrict__ counts) {
    __shared__ int s[NBLK];
    int c = blockIdx.x;
    int t = threadIdx.x;
    int* row = mat + c * NBLK;
    int v = row[t];
    s[t] = v;
    __syncthreads();
    for (int d = 1; d < NBLK; d <<= 1) {
        int val = (t >= d) ? s[t - d] : 0;
        __syncthreads();
        s[t] += val;
        __syncthreads();
    }
    row[t] = s[t] - v;              // exclusive
    if (t == NBLK - 1) counts[c] = s[NBLK - 1];
}

// ---------- phase 2b: class-level exclusive offsets ----------
__global__ void scan_offsets_kernel(const int* __restrict__ counts,
                                    int* __restrict__ offsets) {
    __shared__ int s[1024];
    int t = threadIdx.x;
    int c = (t < C_NUM) ? counts[t] : 0;
    s[t] = c;
    __syncthreads();
    for (int d = 1; d < 1024; d <<= 1) {
        int v = (t >= d) ? s[t - d] : 0;
        __syncthreads();
        s[t] += v;
        __syncthreads();
    }
    if (t < C_NUM) offsets[t] = s[t] - c;   // exclusive
}

// ---------- phase 3: LDS-staged place -> class-contiguous burst writes ----------
__global__ __launch_bounds__(256) void place_staged_kernel(
        const int* __restrict__ labels, int n,
        const int* __restrict__ mat, const int* __restrict__ offsets,
        int* __restrict__ order) {
    __shared__ int h[1024];         // hist, later reused as cursor
    __shared__ int loc[1028];       // exclusive local offsets; loc[1000] = m
    __shared__ int gbase[C_NUM];    // global dest base per class for this chunk
    __shared__ int ps[256];
    __shared__ int stage[STAGE_MAX];
    int b = blockIdx.x;
    int t = threadIdx.x;
    int chunk = (n + NBLK - 1) / NBLK;
    int start = b * chunk, end = min(start + chunk, n);
    int m = end - start;

    for (int i = t; i < 1024; i += 256) h[i] = 0;
    for (int c = t; c < C_NUM; c += 256)
        gbase[c] = offsets[c] + mat[c * NBLK + b];
    __syncthreads();
    for (int i = start + t; i < end; i += 256)
        atomicAdd(&h[labels[i]], 1);
    __syncthreads();

    // exclusive scan of h[0..1023] -> loc, 4 classes per thread
    int c4 = t * 4;
    int a0 = h[c4], a1 = h[c4 + 1], a2 = h[c4 + 2], a3 = h[c4 + 3];
    int ssum = a0 + a1 + a2 + a3;
    ps[t] = ssum;
    __syncthreads();
    for (int d = 1; d < 256; d <<= 1) {
        int v = (t >= d) ? ps[t - d] : 0;
        __syncthreads();
        ps[t] += v;
        __syncthreads();
    }
    int excl = ps[t] - ssum;
    loc[c4]     = excl;
    loc[c4 + 1] = excl + a0;
    loc[c4 + 2] = excl + a0 + a1;
    loc[c4 + 3] = excl + a0 + a1 + a2;
    __syncthreads();

    // reuse h as local cursor
    for (int c = t; c < C_NUM; c += 256) h[c] = loc[c];
    __syncthreads();

    // stage indices into class-sorted local positions
    for (int i = start + t; i < end; i += 256) {
        int lab = labels[i];
        int p = atomicAdd(&h[lab], 1);
        stage[p] = i;
    }
    __syncthreads();

    // write out: consecutive local j within a class run -> consecutive global dest
    for (int j = t; j < m; j += 256) {
        int lo = 0, hi = C_NUM - 1;                // largest c with loc[c] <= j
        while (lo < hi) {
            int mid = (lo + hi + 1) >> 1;
            if (loc[mid] <= j) lo = mid; else hi = mid - 1;
        }
        order[gbase[lo] + (j - loc[lo])] = stage[j];
    }
}

// ---------- fallback place (global atomics) for oversized chunks ----------
__global__ void init_cursor_kernel(const int* __restrict__ offsets,
                                   int* __restrict__ cursor) {
    int i = blockIdx.x * blockDim.x + threadIdx.x;
    if (i < C_NUM) cursor[i] = offsets[i];
}

__global__ void build_order_kernel(const int* __restrict__ labels, int n,
                                   int* __restrict__ cursor,
                                   int* __restrict__ order) {
    int idx = blockIdx.x * blockDim.x + threadIdx.x;
    int stride = gridDim.x * blockDim.x;
    for (int i = idx; i < n; i += stride) {
        int lab = labels[i];
        int pos = atomicAdd(&cursor[lab], 1);
        order[pos] = i;
    }
}

// ---------- phase 4: chunked class gather-reduce, plain slice writes ----------
__global__ __launch_bounds__(256) void partial_reduce_kernel(
        const float4* __restrict__ feat4, const int* __restrict__ order,
        const int* __restrict__ counts, const int* __restrict__ offsets,
        float* __restrict__ sums_part) {
    int c = blockIdx.x >> 5;          // / KCHUNKS
    int k = blockIdx.x & (KCHUNKS - 1);
    int cnt = counts[c];
    int off = offsets[c];
    int len = (cnt + KCHUNKS - 1) / KCHUNKS;
    int start = off + k * len;
    int end = min(start + len, off + cnt);

    int tid = threadIdx.x;
    int sub = tid >> 5;               // 0..7
    int q = tid & 31;                 // float4 lane within row

    __shared__ int ord[SLICE];
    float4 acc = make_float4(0.f, 0.f, 0.f, 0.f);

    for (int base = start; base < end; base += SLICE) {
        int m = min(SLICE, end - base);
        if (tid < m) ord[tid] = order[base + tid];
        __syncthreads();
        int i = sub;
        for (; i + 24 < m; i += 32) {
            int r0 = ord[i], r1 = ord[i + 8], r2 = ord[i + 16], r3 = ord[i + 24];
            float4 v0 = feat4[(long)r0 * 32 + q];
            float4 v1 = feat4[(long)r1 * 32 + q];
            float4 v2 = feat4[(long)r2 * 32 + q];
            float4 v3 = feat4[(long)r3 * 32 + q];
            acc.x += (v0.x + v1.x) + (v2.x + v3.x);
            acc.y += (v0.y + v1.y) + (v2.y + v3.y);
            acc.z += (v0.z + v1.z) + (v2.z + v3.z);
            acc.w += (v0.w + v1.w) + (v2.w + v3.w);
        }
        for (; i < m; i += 8) {
            int r = ord[i];
            float4 v = feat4[(long)r * 32 + q];
            acc.x += v.x; acc.y += v.y; acc.z += v.z; acc.w += v.w;
        }
        __syncthreads();
    }

    __shared__ float4 lds4[256];
    lds4[tid] = acc;
    __syncthreads();
    if (tid < D_DIM) {
        const float* lds = (const float*)lds4;
        float s = 0.f;
        #pragma unroll
        for (int g = 0; g < 8; ++g) s += lds[g * D_DIM + tid];
        sums_part[((long)k * C_NUM + c) * D_DIM + tid] = s;  // plain store
    }
}

// ---------- phase 5: reduce slices + EMA epilogue ----------
__global__ __launch_bounds__(128) void finalize_slices_kernel(
        const float* __restrict__ prototypes, const float* __restrict__ sums_part,
        const int* __restrict__ counts, float* __restrict__ out) {
    __shared__ float red[D_DIM];
    int c = blockIdx.x, d = threadIdx.x;
    float s = 0.f;
    #pragma unroll 8
    for (int k = 0; k < KCHUNKS; ++k)
        s += sums_part[((long)k * C_NUM + c) * D_DIM + d];
    float proto = prototypes[c * D_DIM + d];
    red[d] = proto;
    __syncthreads();
    for (int t = 64; t > 0; t >>= 1) {
        if (d < t) red[d] += red[d + t];
        __syncthreads();
    }
    float rowsum = red[0];
    int cnt = counts[c];
    float mean = s / (float)max(cnt, 1);
    float ema = MOMENTUM * proto + (1.f - MOMENTUM) * mean;
    out[c * D_DIM + d] = (cnt > 0) ? ((rowsum == 0.f) ? mean : ema) : proto;
}

// ===================== fallback (atomic path, small ws) =====================
__global__ void zero_ws_words_kernel(int* __restrict__ ws, int n) {
    int i = blockIdx.x * blockDim.x + threadIdx.x;
    if (i < n) ws[i] = 0;
}

__global__ void hist_kernel(const int* __restrict__ labels, int n,
                            int* __restrict__ counts) {
    __shared__ int h[C_NUM];
    for (int i = threadIdx.x; i < C_NUM; i += blockDim.x) h[i] = 0;
    __syncthreads();
    int idx = blockIdx.x * blockDim.x + threadIdx.x;
    int stride = gridDim.x * blockDim.x;
    for (int i = idx; i < n; i += stride) atomicAdd(&h[labels[i]], 1);
    __syncthreads();
    for (int i = threadIdx.x; i < C_NUM; i += blockDim.x) {
        int v = h[i];
        if (v) atomicAdd(&counts[i], v);
    }
}

__global__ void scatter_kernel(const float4* __restrict__ feat4,
                               const int* __restrict__ labels,
                               float* __restrict__ sums, long total4) {
    long idx = (long)blockIdx.x * blockDim.x + threadIdx.x;
    long stride = (long)gridDim.x * blockDim.x;
    for (long i = idx; i < total4; i += stride) {
        float4 v = feat4[i];
        int row = (int)(i >> 5);
        int q = (int)(i & 31);
        int lab = labels[row];
        float* dst = sums + lab * D_DIM + q * 4;
        atomicAdd(dst + 0, v.x);
        atomicAdd(dst + 1, v.y);
        atomicAdd(dst + 2, v.z);
        atomicAdd(dst + 3, v.w);
    }
}

__global__ void finalize_kernel(const float* __restrict__ prototypes,
                                const float* __restrict__ sums,
                                const int* __restrict__ counts,
                                float* __restrict__ out) {
    __shared__ float red[D_DIM];
    int c = blockIdx.x;
    int d = threadIdx.x;
    float proto = prototypes[c * D_DIM + d];
    red[d] = proto;
    __syncthreads();
    for (int s = 64; s > 0; s >>= 1) {
        if (d < s) red[d] += red[d + s];
        __syncthreads();
    }
    float rowsum = red[0];
    int cnt = counts[c];
    float mean = sums[c * D_DIM + d] / (float)max(cnt, 1);
    float ema = MOMENTUM * proto + (1.0f - MOMENTUM) * mean;
    out[c * D_DIM + d] = (cnt > 0) ? ((rowsum == 0.0f) ? mean : ema) : proto;
}

// =========================================================================
extern "C" void kernel_launch(void* const* d_in, const int* in_sizes, int n_in,
                              void* d_out, int out_size, void* d_ws, size_t ws_size,
                              hipStream_t stream) {
    const float* features   = (const float*)d_in[0];
    const int*   labels     = (const int*)d_in[1];
    const float* prototypes = (const float*)d_in[2];
    float* out = (float*)d_out;
    int n = in_sizes[1];

    int* counts      = (int*)d_ws;
    int* offsets     = counts + C_NUM;
    int* cursor      = offsets + C_NUM;
    int* mat         = cursor + C_NUM;
    float* sums_part = (float*)(mat + (size_t)C_NUM * NBLK);
    int* order       = (int*)(sums_part + (size_t)KCHUNKS * C_NUM * D_DIM);

    size_t need = ((size_t)3 * C_NUM + (size_t)C_NUM * NBLK +
                   (size_t)KCHUNKS * C_NUM * D_DIM + (size_t)n) * sizeof(int);
    if (ws_size >= need) {
        int chunk = (n + NBLK - 1) / NBLK;
        chunk_hist_kernel<<<NBLK, 256, 0, stream>>>(labels, n, mat);
        scan_mat_kernel<<<C_NUM, NBLK, 0, stream>>>(mat, counts);
        scan_offsets_kernel<<<1, 1024, 0, stream>>>(counts, offsets);
        if (chunk <= STAGE_MAX) {
            place_staged_kernel<<<NBLK, 256, 0, stream>>>(labels, n, mat, offsets, order);
        } else {
            init_cursor_kernel<<<(C_NUM + 255) / 256, 256, 0, stream>>>(offsets, cursor);
            build_order_kernel<<<1024, 256, 0, stream>>>(labels, n, cursor, order);
        }
        partial_reduce_kernel<<<C_NUM * KCHUNKS, 256, 0, stream>>>(
            (const float4*)features, order, counts, offsets, sums_part);
        finalize_slices_kernel<<<C_NUM, D_DIM, 0, stream>>>(
            prototypes, sums_part, counts, out);
    } else {
        float* fsums = (float*)d_ws;
        int* fcounts = (int*)(fsums + C_NUM * D_DIM);
        int zero_n = C_NUM * D_DIM + C_NUM;
        zero_ws_words_kernel<<<(zero_n + 255) / 256, 256, 0, stream>>>((int*)d_ws, zero_n);
        hist_kernel<<<512, 256, 0, stream>>>(labels, n, fcounts);
        long total4 = (long)n * (D_DIM / 4);
        scatter_kernel<<<2048, 256, 0, stream>>>((const float4*)features, labels, fsums, total4);
        finalize_kernel<<<C_NUM, D_DIM, 0, stream>>>(prototypes, fsums, fcounts, out);
    }
}